// Round 7
// baseline (763.792 us; speedup 1.0000x reference)
//
#include <hip/hip_runtime.h>
#include <hip/hip_bf16.h>
#include <cstdint>
#include <cstddef>

// Problem constants
#define WE    300
#define TEF   10
#define SLEN  24
#define HL    75      // H_LSTM
#define G4    300     // 4*HL
#define HG    77      // H_GRU
#define G3    231     // 3*HG
#define CLS   27
#define DIN   7210
#define NSTEP 4608
#define SEG   96      // owned steps per segment
#define LBI   16      // burn-in (worst-case window start gets >=11 steps; negligible)

typedef short    s16x8 __attribute__((ext_vector_type(8)));
typedef float    f32x4 __attribute__((ext_vector_type(4)));
typedef _Float16 h2_t  __attribute__((ext_vector_type(2)));

static __device__ __forceinline__ unsigned short f2bf(float f) {
  unsigned u = __builtin_bit_cast(unsigned, f);
  unsigned r = u + 0x7fffu + ((u >> 16) & 1u);   // RNE
  return (unsigned short)(r >> 16);
}
static __device__ __forceinline__ unsigned packbf(float a, float b) {
  return (unsigned)f2bf(a) | ((unsigned)f2bf(b) << 16);
}

static __device__ __forceinline__ float fast_exp2(float x) {
#if __has_builtin(__builtin_amdgcn_exp2f)
  return __builtin_amdgcn_exp2f(x);
#else
  return __exp2f(x);
#endif
}
static __device__ __forceinline__ float fast_rcp(float x) {
#if __has_builtin(__builtin_amdgcn_rcpf)
  return __builtin_amdgcn_rcpf(x);
#else
  return 1.0f / x;
#endif
}
static __device__ __forceinline__ float sigm(float x) {
  return fast_rcp(1.0f + fast_exp2(-1.4426950408889634f * x));
}
static __device__ __forceinline__ float tanh_f(float x) {
  return 2.0f * fast_rcp(1.0f + fast_exp2(-2.8853900817779268f * x)) - 1.0f;
}

// LDS-only barrier (keeps global loads in flight)
static __device__ __forceinline__ void lds_barrier() {
  __asm__ volatile("s_waitcnt lgkmcnt(0)\n\ts_barrier" ::: "memory");
}

#if __has_builtin(__builtin_amdgcn_update_dpp)
static __device__ __forceinline__ float qxor1(float v) {
  return __builtin_bit_cast(float, __builtin_amdgcn_update_dpp(0, __builtin_bit_cast(int, v), 177, 0xf, 0xf, false));
}
static __device__ __forceinline__ float qxor2(float v) {
  return __builtin_bit_cast(float, __builtin_amdgcn_update_dpp(0, __builtin_bit_cast(int, v), 78, 0xf, 0xf, false));
}
static __device__ __forceinline__ float qxor3(float v) {
  return __builtin_bit_cast(float, __builtin_amdgcn_update_dpp(0, __builtin_bit_cast(int, v), 27, 0xf, 0xf, false));
}
#else
static __device__ __forceinline__ float qxor1(float v) { return __shfl_xor(v, 1, 64); }
static __device__ __forceinline__ float qxor2(float v) { return __shfl_xor(v, 2, 64); }
static __device__ __forceinline__ float qxor3(float v) { return __shfl_xor(v, 3, 64); }
#endif

#if __has_builtin(__builtin_amdgcn_fdot2)
#define FDOT2(a, b, c) __builtin_amdgcn_fdot2((a), (b), (c), false)
#else
#define FDOT2(a, b, c) ((c) + (float)(a).x * (float)(b).x + (float)(a).y * (float)(b).y)
#endif

// ---------------------------------------------------------------------------
// Wt[n][k] = lstm_W[k][n], bf16, zero-padded to 320x320 (L2-resident, 205 KB)
// ---------------------------------------------------------------------------
__global__ __launch_bounds__(256) void k_prep_wt(const float* __restrict__ W,
                                                 unsigned short* __restrict__ Wt) {
  int idx = blockIdx.x * 256 + threadIdx.x;
  if (idx >= 320 * 320) return;
  int n = idx / 320, k = idx - n * 320;
  float v = (n < G4 && k < WE) ? W[k * G4 + n] : 0.0f;
  Wt[idx] = f2bf(v);
}

// ---------------------------------------------------------------------------
// K2: FUSED segmented LSTM. grid (24 chains, 48 segments), 128 threads.
// Per block: two phases of {local MFMA GEMM (<=56 steps x 300 cols of x@W
// into LDS f16) ; recurrence over those steps}. No XWc global buffer.
// Recurrence: quad Q owns elements {Q, Q+32, Q+64(<75)}; lane = gate.
// ---------------------------------------------------------------------------
#define LSTM_DOT3()                                                                    \
  {                                                                                    \
    float a00 = 0.f, a01 = 0.f, a02 = 0.f, a03 = 0.f;                                  \
    float a10 = 0.f, a11 = 0.f, a12 = 0.f, a13 = 0.f;                                  \
    float a20 = 0.f, a21 = 0.f, a22 = 0.f, a23 = 0.f;                                  \
    _Pragma("unroll")                                                                  \
    for (int p = 0; p < 10; ++p) {                                                     \
      uint4 w = hb[p];                                                                 \
      h2_t wx = __builtin_bit_cast(h2_t, w.x), wy = __builtin_bit_cast(h2_t, w.y);     \
      h2_t wz = __builtin_bit_cast(h2_t, w.z), ww = __builtin_bit_cast(h2_t, w.w);     \
      a00 = FDOT2(u0[4 * p + 0], wx, a00); a01 = FDOT2(u0[4 * p + 1], wy, a01);        \
      a02 = FDOT2(u0[4 * p + 2], wz, a02); a03 = FDOT2(u0[4 * p + 3], ww, a03);        \
      a10 = FDOT2(u1[4 * p + 0], wx, a10); a11 = FDOT2(u1[4 * p + 1], wy, a11);        \
      a12 = FDOT2(u1[4 * p + 2], wz, a12); a13 = FDOT2(u1[4 * p + 3], ww, a13);        \
      a20 = FDOT2(u2v[4 * p + 0], wx, a20); a21 = FDOT2(u2v[4 * p + 1], wy, a21);      \
      a22 = FDOT2(u2v[4 * p + 2], wz, a22); a23 = FDOT2(u2v[4 * p + 3], ww, a23);      \
    }                                                                                  \
    z0 = (a00 + a01) + (a02 + a03);                                                    \
    z1 = (a10 + a11) + (a12 + a13);                                                    \
    z2 = (a20 + a21) + (a22 + a23);                                                    \
  }

#define LSTM_ACT(Z, C, H)                                                              \
  {                                                                                    \
    float ss = fast_rcp(1.0f + fast_exp2((Z)*km));                                     \
    float act = isg ? (2.0f * ss - 1.0f) : ss;                                         \
    float fg = qxor1(act);                                                             \
    float gg = qxor2(act);                                                             \
    float og = qxor3(act);                                                             \
    (C) = fmaf(fg, (C), act * gg);                                                     \
    (H) = og * tanh_f((C));                                                            \
  }

#define LSTM_STEP(I, PAR)                                                              \
  {                                                                                    \
    const uint4* hb = (const uint4*)(&hbuf[PAR][0]);                                   \
    const unsigned short* xr = &XWh[(m + (I)) * 304];                                  \
    float xv0 = (float)__builtin_bit_cast(_Float16, xr[c0]);                           \
    float xv1 = (float)__builtin_bit_cast(_Float16, xr[c1]);                           \
    float xv2 = (float)__builtin_bit_cast(_Float16, xr[c2]);                           \
    float z0, z1, z2;                                                                  \
    LSTM_DOT3()                                                                        \
    z0 += bj0 + xv0; z1 += bj1 + xv1; z2 += bj2 + xv2;                                 \
    LSTM_ACT(z0, c0r, h0r)                                                             \
    LSTM_ACT(z1, c1r, h1r)                                                             \
    LSTM_ACT(z2, c2r, h2r)                                                             \
    if (g == 0) {                                                                      \
      unsigned short* hw = &hbuf[(PAR) ^ 1][0];                                        \
      hw[e0] = __builtin_bit_cast(unsigned short, (_Float16)h0r);                      \
      hw[e1] = __builtin_bit_cast(unsigned short, (_Float16)h1r);                      \
      if (has2) hw[e2] = __builtin_bit_cast(unsigned short, (_Float16)h2r);            \
      int ng = start + ph_off + m + (I);                                               \
      int bi = ng / 18;                                                                \
      int rr = ng - bi * 18;                                                           \
      if (rr >= 12) {                                                                  \
        float aw = A_lds[rr - 12];                                                     \
        accA0 = fmaf(aw, h0r, accA0);                                                  \
        accA1 = fmaf(aw, h1r, accA1);                                                  \
        accA2 = fmaf(aw, h2r, accA2);                                                  \
        if (rr == 17) {                                                                \
          if (ng >= out_lo) {                                                          \
            float* Pp = P + ((size_t)((t << 8) + bi)) * 76;                            \
            Pp[e0] = accA0; Pp[e1] = accA1;                                            \
            if (has2) Pp[e2] = accA2;                                                  \
          }                                                                            \
          accA0 = 0.f; accA1 = 0.f; accA2 = 0.f;                                       \
        }                                                                              \
      }                                                                                \
    }                                                                                  \
    lds_barrier();                                                                     \
  }

__global__ __launch_bounds__(128, 2) void k_lstm(const float* __restrict__ X,
                                                 const unsigned short* __restrict__ Wt,
                                                 const float* __restrict__ U,
                                                 const float* __restrict__ bvec,
                                                 const float* __restrict__ Atw,
                                                 float* __restrict__ P) {
  __shared__ __align__(16) unsigned short XWh[56 * 304];   // f16 x@W tile, 34 KB
  __shared__ __align__(16) unsigned short hbuf[2][80];
  __shared__ float A_lds[8];
  const int tid = threadIdx.x;          // 0..127
  const int t = blockIdx.x;
  const int seg = blockIdx.y;
  const int wave = tid >> 6, lane = tid & 63;
  const int mrow = lane & 15, q4 = lane >> 4;
  const int g = tid & 3;
  const int Q = tid >> 2;               // 0..31
  const bool isg = (g == 2);
  const float km = isg ? -2.8853900817779268f : -1.4426950408889634f;

  const int e0 = Q, e1 = Q + 32, e2 = Q + 64;
  const bool has2 = (e2 < HL);
  const int c0 = g * 75 + e0;
  const int c1 = g * 75 + e1;
  const int c2 = g * 75 + (has2 ? e2 : e0);   // dup col when absent (writes guarded)

  const int start = seg * SEG - (seg ? LBI : 0);
  const int count = SEG + (seg ? LBI : 0);    // 96 or 112
  const int out_lo = seg * SEG;
  const int hs0 = count >> 1;                 // 48 or 56

  if (tid < 6) A_lds[tid] = Atw[tid];
  if (tid < 80) { hbuf[0][tid] = 0; hbuf[1][tid] = 0; }

  // U columns as f16 pairs (40 h2 each, zero-padded past 75)
  h2_t u0[40], u1[40], u2v[40];
#pragma unroll
  for (int p = 0; p < 40; ++p) {
    float va0 = (2 * p < HL) ? U[(2 * p) * G4 + c0] : 0.f;
    float vb0 = (2 * p + 1 < HL) ? U[(2 * p + 1) * G4 + c0] : 0.f;
    float va1 = (2 * p < HL) ? U[(2 * p) * G4 + c1] : 0.f;
    float vb1 = (2 * p + 1 < HL) ? U[(2 * p + 1) * G4 + c1] : 0.f;
    float va2 = (2 * p < HL) ? U[(2 * p) * G4 + c2] : 0.f;
    float vb2 = (2 * p + 1 < HL) ? U[(2 * p + 1) * G4 + c2] : 0.f;
    h2_t w;
    w.x = (_Float16)va0; w.y = (_Float16)vb0; u0[p] = w;
    w.x = (_Float16)va1; w.y = (_Float16)vb1; u1[p] = w;
    w.x = (_Float16)va2; w.y = (_Float16)vb2; u2v[p] = w;
  }
  const float bj0 = bvec[c0], bj1 = bvec[c1], bj2 = bvec[c2];

  float c0r = 0.f, c1r = 0.f, c2r = 0.f;
  float h0r = 0.f, h1r = 0.f, h2r = 0.f;
  float accA0 = 0.f, accA1 = 0.f, accA2 = 0.f;

  if (g == 0) {  // segments always start from zero state (seg0 exact; others burn in)
    hbuf[0][e0] = 0; hbuf[0][e1] = 0;
    if (has2) hbuf[0][e2] = 0;
  }

  int ph_off = 0;
  for (int phase = 0; phase < 2; ++phase) {
    const int hs = phase ? (count - hs0) : hs0;   // 48 or 56
    const int mtiles = (hs + 15) >> 4;            // 3 or 4
    __syncthreads();

    // ---- GEMM phase: XWh[m][n] = x_{start+ph_off+m, t} @ W  (bf16 MFMA) ----
    for (int mi = wave; mi < mtiles; mi += 2) {
      f32x4 acc[19];
#pragma unroll
      for (int ni = 0; ni < 19; ++ni) { acc[ni][0] = 0.f; acc[ni][1] = 0.f; acc[ni][2] = 0.f; acc[ni][3] = 0.f; }
      int m = mi * 16 + mrow;
      int n = start + ph_off + ((m < hs) ? m : 0);   // clamp: junk row, not stored
      const float* ar = X + (size_t)n * DIN + t * WE;
      for (int kb = 0; kb < 10; ++kb) {
        s16x8 af;
        {
          float av[8];
          if (kb < 9) {
            const float2* a2 = (const float2*)(ar + kb * 32 + q4 * 8);
            float2 v0 = a2[0], v1 = a2[1], v2 = a2[2], v3 = a2[3];
            av[0] = v0.x; av[1] = v0.y; av[2] = v1.x; av[3] = v1.y;
            av[4] = v2.x; av[5] = v2.y; av[6] = v3.x; av[7] = v3.y;
          } else {
#pragma unroll
            for (int j = 0; j < 8; ++j) {
              int k = 288 + q4 * 8 + j;
              av[j] = (k < WE) ? ar[k] : 0.f;
            }
          }
          uint4 pk;
          pk.x = packbf(av[0], av[1]); pk.y = packbf(av[2], av[3]);
          pk.z = packbf(av[4], av[5]); pk.w = packbf(av[6], av[7]);
          af = __builtin_bit_cast(s16x8, pk);
        }
        const unsigned short* bp = Wt + (size_t)mrow * 320 + kb * 32 + q4 * 8;
#pragma unroll
        for (int ni = 0; ni < 19; ++ni) {
          s16x8 bf = __builtin_bit_cast(s16x8, *(const uint4*)(bp + ni * 5120));
          acc[ni] = __builtin_amdgcn_mfma_f32_16x16x32_bf16(af, bf, acc[ni], 0, 0, 0);
        }
      }
      // C layout: col = ni*16 + (lane&15), row = mi*16 + q4*4 + reg
#pragma unroll
      for (int reg = 0; reg < 4; ++reg) {
        int row = mi * 16 + q4 * 4 + reg;
        if (row < hs) {
          unsigned short* xw = &XWh[row * 304 + mrow];
#pragma unroll
          for (int ni = 0; ni < 19; ++ni)
            xw[ni * 16] = __builtin_bit_cast(unsigned short, (_Float16)acc[ni][reg]);
        }
      }
    }
    __syncthreads();

    // ---- recurrence phase over hs steps (reads XWh + hbuf from LDS) ----
    for (int m = 0; m < hs; m += 4) {
      LSTM_STEP(0, 0)
      LSTM_STEP(1, 1)
      LSTM_STEP(2, 0)
      LSTM_STEP(3, 1)
    }
    ph_off += hs;
  }
}

// ---------------------------------------------------------------------------
// K3: hA -> ctx (ut==2) -> xg = ctx@gru_W + gru_b[0]. grid 256, 320 thr.
// ---------------------------------------------------------------------------
__global__ __launch_bounds__(320) void k_ctx(const float* __restrict__ P,
                                             const float* __restrict__ Wtw,
                                             const float* __restrict__ btw,
                                             const float* __restrict__ Atw,
                                             const float* __restrict__ Btw,
                                             const float* __restrict__ X,
                                             const float* __restrict__ Wg,
                                             const float* __restrict__ bg,
                                             float* __restrict__ xg) {
  __shared__ float hA[76];
  __shared__ float ctx[312];
  const int b = blockIdx.x, j = threadIdx.x;
  if (j < HL) {
    float s = 0.f;
    for (int t = 0; t < SLEN; ++t) s += P[((t << 8) + b) * 76 + j];
    hA[j] = s * (1.0f / 24.0f);
  }
  __syncthreads();
  if (j < G4) {
    float SA = Atw[0] + Atw[1] + Atw[2] + Atw[3] + Atw[4] + Atw[5];
    float s = SA * btw[j];
    for (int k = 0; k < HL; ++k) s = fmaf(hA[k], Wtw[k * G4 + j], s);
    ctx[j] = s * (1000.0f / 1001.0f) + Btw[0];
  } else if (j < 310) {
    int f = j - G4;
    float s = 0.f;
#pragma unroll
    for (int nt = 0; nt < 6; ++nt)
      s = fmaf(Atw[nt], X[(size_t)((b * 3 + 2) * 6 + nt) * DIN + 7200 + f], s);
    ctx[j] = s * (1.0f / 1001.0f) + Btw[0];
  }
  __syncthreads();
  if (j < G3) {
    float s = bg[j];
    for (int f = 0; f < 310; ++f) s = fmaf(ctx[f], Wg[f * G3 + j], s);
    xg[b * 240 + j] = s;
  }
}

// ---------------------------------------------------------------------------
// K5: segmented GRU (chain ut==2). grid 16 blocks x 256 thr.
// ---------------------------------------------------------------------------
#define GRU_STEP(B, PF)                                                                \
  {                                                                                    \
    if (q < G3) {                                                                      \
      const float4* h4 = (const float4*)gh;                                            \
      float a0 = b1, a1 = 0.f, a2 = 0.f, a3 = 0.f;                                     \
      _Pragma("unroll")                                                                \
      for (int p = 0; p < 20; ++p) {                                                   \
        float4 hv = h4[p];                                                             \
        a0 = fmaf(ug[4 * p + 0], hv.x, a0);                                            \
        a1 = fmaf(ug[4 * p + 1], hv.y, a1);                                            \
        a2 = fmaf(ug[4 * p + 2], hv.z, a2);                                            \
        a3 = fmaf(ug[4 * p + 3], hv.w, a3);                                            \
      }                                                                                \
      float rs = (a0 + a1) + (a2 + a3);                                                \
      float pnew = ((B) + 2 < 256) ? xg[((B) + 2) * 240 + q] : 0.f;                    \
      if (q < HG) {                                                                    \
        zreg = sigm((PF) + rs);                                                        \
      } else if (q < 154) {                                                            \
        rbuf[q - 77] = sigm((PF) + rs);                                                \
      } else {                                                                         \
        xkeep = (PF);                                                                  \
        rkeep = rs;                                                                    \
      }                                                                                \
      (PF) = pnew;                                                                     \
    }                                                                                  \
    lds_barrier();                                                                     \
    if (q >= 154 && q < G3) hhb[q - 154] = tanh_f(xkeep + rbuf[q - 154] * rkeep);      \
    lds_barrier();                                                                     \
    if (q < HG) {                                                                      \
      float hh = hhb[q];                                                               \
      hq = zreg * hq + (1.0f - zreg) * hh;                                             \
      gh[q] = hq;                                                                      \
      if ((B) >= out_lo) Hg[(B) * 80 + q] = hq;                                        \
    }                                                                                  \
    lds_barrier();                                                                     \
  }

__global__ __launch_bounds__(256) void k_gru(const float* __restrict__ Ug,
                                             const float* __restrict__ bg,
                                             const float* __restrict__ xg,
                                             float* __restrict__ Hg) {
  __shared__ __align__(16) float gh[80];
  __shared__ float rbuf[77];
  __shared__ float hhb[77];
  const int q = threadIdx.x;
  const int b0 = blockIdx.x;
  const int out_lo = b0 * 16;
  const int start = b0 ? (out_lo - 16) : 0;
  const int end = out_lo + 16;
  float ug[80];
  float b1 = 0.f;
  if (q < G3) {
    b1 = bg[G3 + q];
#pragma unroll
    for (int k = 0; k < 80; ++k) ug[k] = (k < HG) ? Ug[k * G3 + q] : 0.f;
  }
  if (q < 80) gh[q] = 0.f;
  float hq = 0.f, zreg = 0.f, xkeep = 0.f, rkeep = 0.f;
  float pf0 = (q < G3) ? xg[start * 240 + q] : 0.f;
  float pf1 = (q < G3) ? xg[(start + 1) * 240 + q] : 0.f;
  __syncthreads();
  for (int b = start; b < end; b += 2) {
    GRU_STEP(b, pf0)
    GRU_STEP(b + 1, pf1)
  }
}

// ---------------------------------------------------------------------------
__global__ __launch_bounds__(64) void k_out(const float* __restrict__ Hg,
                                            const float* __restrict__ Wl,
                                            const float* __restrict__ bl,
                                            float* __restrict__ out) {
  __shared__ float lb[CLS];
  __shared__ float eb[CLS];
  const int b = blockIdx.x, j = threadIdx.x;
  float lg = 0.f;
  if (j < CLS) {
    lg = bl[j];
    for (int k = 0; k < HG; ++k) lg = fmaf(Hg[b * 80 + k], Wl[k * CLS + j], lg);
    lb[j] = lg;
  }
  __syncthreads();
  float ex = 0.f;
  if (j < CLS) {
    float m = lb[0];
    for (int i = 1; i < CLS; ++i) m = fmaxf(m, lb[i]);
    ex = fast_exp2((lg - m) * 1.4426950408889634f);
    eb[j] = ex;
  }
  __syncthreads();
  if (j < CLS) {
    float s = 0.f;
    for (int i = 0; i < CLS; ++i) s += eb[i];
    out[b * CLS + j] = ex / s;
  }
}

// ---------------------------------------------------------------------------
extern "C" void kernel_launch(void* const* d_in, const int* in_sizes, int n_in,
                              void* d_out, int out_size, void* d_ws, size_t ws_size,
                              hipStream_t stream) {
  const float* X    = (const float*)d_in[0];
  const float* lW   = (const float*)d_in[1];
  const float* lU   = (const float*)d_in[2];
  const float* lb   = (const float*)d_in[3];
  const float* twW  = (const float*)d_in[4];
  const float* twb  = (const float*)d_in[5];
  const float* Atw  = (const float*)d_in[6];
  const float* Btw  = (const float*)d_in[7];
  const float* gW   = (const float*)d_in[8];
  const float* gU   = (const float*)d_in[9];
  const float* gb   = (const float*)d_in[10];
  const float* linW = (const float*)d_in[11];
  const float* linb = (const float*)d_in[12];
  float* out = (float*)d_out;

  char* ws = (char*)d_ws;
  unsigned short* Wt = (unsigned short*)(ws + 0);        // 204800
  float* P   = (float*)(ws + 204800);                    // 24*256*76*4 = 1867776
  float* xg  = (float*)(ws + 2072576);                   // 245760
  float* Hg  = (float*)(ws + 2318336);                   // 81920
  // total ~2.4 MB — no XWc, no chunking

  k_prep_wt<<<dim3(400), dim3(256), 0, stream>>>(lW, Wt);
  k_lstm<<<dim3(24, NSTEP / SEG), dim3(128), 0, stream>>>(X, Wt, lU, lb, Atw, P);
  k_ctx<<<dim3(256), dim3(320), 0, stream>>>(P, twW, twb, Atw, Btw, X, gW, gb, xg);
  k_gru<<<dim3(16), dim3(256), 0, stream>>>(gU, gb, xg, Hg);
  k_out<<<dim3(256), dim3(64), 0, stream>>>(Hg, linW, linb, out);
}